// Round 17
// baseline (220.868 us; speedup 1.0000x reference)
//
#include <hip/hip_runtime.h>
#include <hip/hip_bf16.h>
#include <cstddef>
#include <cstdint>

#define NB 16
#define LIN 512
#define DM 384
#define DC 1536
#define MELMAX 4096
#define LN_EPS 1e-5f

typedef __bf16 bf16x8 __attribute__((ext_vector_type(8)));
typedef float f32x4 __attribute__((ext_vector_type(4)));

#define GL2LDS(gp, lp)                                                                \
    __builtin_amdgcn_global_load_lds((const __attribute__((address_space(1))) void*)(gp), \
                                     (__attribute__((address_space(3))) void*)(lp), 16, 0, 0)

__device__ __forceinline__ float wred(float v) {
#pragma unroll
    for (int m = 32; m >= 1; m >>= 1) v += __shfl_xor(v, m, 64);
    return v;
}

__device__ __forceinline__ unsigned short f2bf(float f) {
    __hip_bfloat16 h = __float2bfloat16(f);
    return *reinterpret_cast<unsigned short*>(&h);
}

__device__ __forceinline__ float bf2f(unsigned short u) {
    return __uint_as_float(((unsigned)u) << 16);
}

// ---------------------------------------------------------------- length-regulate gather (standalone)

__global__ __launch_bounds__(256) void gather_kernel(const float* __restrict__ x,
                                                     const int* __restrict__ cum,
                                                     float* __restrict__ out) {
    const int wid = (blockIdx.x * 256 + threadIdx.x) >> 6;
    const int lane = threadIdx.x & 63;
    const int b = wid >> 12;
    const int t = wid & (MELMAX - 1);
    const int* c = cum + b * LIN;
    const int total = c[LIN - 1];
    float4* orow = reinterpret_cast<float4*>(out + ((size_t)b * MELMAX + t) * DM);
    if (t < total) {
        int lo = 0, hi = LIN;
        while (lo < hi) { int mid = (lo + hi) >> 1; if (c[mid] > t) hi = mid; else lo = mid + 1; }
        const int idx = lo < (LIN - 1) ? lo : (LIN - 1);
        const float4* xrow = reinterpret_cast<const float4*>(x + ((size_t)b * LIN + idx) * DM);
#pragma unroll
        for (int j = 0; j < 2; ++j) {
            const int p = lane + 64 * j;
            if (p < DM / 4) orow[p] = xrow[p];
        }
    } else {
        const float4 z = make_float4(0.f, 0.f, 0.f, 0.f);
#pragma unroll
        for (int j = 0; j < 2; ++j) {
            const int p = lane + 64 * j;
            if (p < DM / 4) orow[p] = z;
        }
    }
}

// ---------------------------------------------------------------- fused prep: zpad + cast_x + wcast + cumsum

#define ZPAD_BLKS 96
#define CASTX_BLKS 3072   // NB*LIN*DM/4/256
#define WCAST_BLKS 288    // DC*DM/8/256 per matrix
#define PREP_TOTAL (ZPAD_BLKS + CASTX_BLKS + 4 * WCAST_BLKS + NB)

__global__ void prep_kernel(const float* __restrict__ x, unsigned short* __restrict__ xb,
                            unsigned short* __restrict__ hbig, unsigned short* __restrict__ h2b,
                            const float* __restrict__ w1, const float* __restrict__ w2,
                            const float* __restrict__ w3, const float* __restrict__ w4,
                            unsigned short* __restrict__ o1, unsigned short* __restrict__ o2,
                            unsigned short* __restrict__ o3, unsigned short* __restrict__ o4,
                            const int* __restrict__ tgt, int* __restrict__ cum) {
    const int bid = blockIdx.x, tid = threadIdx.x;
    if (bid < ZPAD_BLKS) {
        const int buf = bid >> 5, rem = bid & 31;
        const int b = rem >> 1, row = (rem & 1) ? (LIN + 1) : 0;
        unsigned short* p = buf == 0 ? xb : (buf == 1 ? hbig : h2b);
        const int rl = buf == 1 ? DC : DM;
        unsigned short* base = p + ((size_t)b * (LIN + 2) + row) * rl;
        for (int c = tid; c < rl; c += 256) base[c] = 0;
        return;
    }
    if (bid < ZPAD_BLKS + CASTX_BLKS) {
        const int idx = (bid - ZPAD_BLKS) * 256 + tid;
        const float4 v = reinterpret_cast<const float4*>(x)[idx];
        const int e = idx * 4;
        const int b = e / (LIN * DM);
        const int rem = e - b * (LIN * DM);
        const int l = rem / DM;
        const int c = rem - l * DM;
        ushort4 o;
        o.x = f2bf(v.x); o.y = f2bf(v.y); o.z = f2bf(v.z); o.w = f2bf(v.w);
        *reinterpret_cast<ushort4*>(xb + ((size_t)b * (LIN + 2) + l + 1) * DM + c) = o;
        return;
    }
    if (bid < ZPAD_BLKS + CASTX_BLKS + 4 * WCAST_BLKS) {
        const int j = bid - ZPAD_BLKS - CASTX_BLKS;
        const int which = j / WCAST_BLKS;
        const int idx = (j - which * WCAST_BLKS) * 256 + tid;   // (co, ci-octet)
        const float* w = which == 0 ? w1 : which == 1 ? w2 : which == 2 ? w3 : w4;
        unsigned short* gg = which == 0 ? o1 : which == 1 ? o2 : which == 2 ? o3 : o4;
        const int CI = (which == 0 || which == 2) ? DM : DC;
        const int OCT = CI / 8;
        const int co = idx / OCT, ci0 = (idx - co * OCT) * 8;
        const float4* p4 = reinterpret_cast<const float4*>(w + (size_t)(co * CI + ci0) * 3);
        float v[24];
#pragma unroll
        for (int q = 0; q < 6; ++q) *reinterpret_cast<float4*>(&v[q * 4]) = p4[q];
        unsigned short tmp[3][8];
#pragma unroll
        for (int e = 0; e < 24; ++e) tmp[e % 3][e / 3] = f2bf(v[e]);
        unsigned short* ob = gg + (size_t)co * (3 * CI) + ci0;
#pragma unroll
        for (int t = 0; t < 3; ++t)
            *reinterpret_cast<uint4*>(ob + (size_t)t * CI) = *reinterpret_cast<const uint4*>(tmp[t]);
        return;
    }
    // ---- cumsum: one block per batch (256 threads, 512 elems)
    {
        const int b = bid - (ZPAD_BLKS + CASTX_BLKS + 4 * WCAST_BLKS);
        __shared__ int s[LIN];
        s[tid] = tgt[b * LIN + tid];
        s[tid + 256] = tgt[b * LIN + tid + 256];
        __syncthreads();
        for (int off = 1; off < LIN; off <<= 1) {
            int v0 = (tid >= off) ? s[tid - off] : 0;
            int v1 = (tid + 256 >= off) ? s[tid + 256 - off] : 0;
            __syncthreads();
            s[tid] += v0;
            s[tid + 256] += v1;
            __syncthreads();
        }
        cum[b * LIN + tid] = s[tid];
        cum[b * LIN + tid + 256] = s[tid + 256];
    }
}

// ---------------------------------------------------------------- conv1d(k=3,SAME) as bf16 MFMA GEMM
// R7-exact: tap-merged A+B LDS staging, counted-vmcnt 2-deep pipeline (raw
// s_barrier, loads in flight across barriers, never vmcnt(0) in loop),
// XCD-chunked swizzle, sched_barrier-pinned protocol. Per-wave stage loads
// uniform: BN=128 -> A3+B6 -> vmcnt(9); BN=64 -> A3+B3 -> vmcnt(6).

template <int CI, int CO, int BN>
__global__ __launch_bounds__(256, 2) void conv_mfma_kernel(const unsigned short* __restrict__ in,
                                                           const unsigned short* __restrict__ wg,
                                                           const float* __restrict__ bias,
                                                           unsigned short* __restrict__ out) {
    constexpr int BM = 128, BK = 32;
    constexpr int KC = CI / BK;             // K-blocks (12 or 48, even)
    constexpr int AGRP = 12;                // padded (only first 9 carry real rows)
    constexpr int GPT = BN / 16;            // row-groups per B tap tile
    constexpr int BGRP = 3 * GPT;           // 24 (BN=128) / 12 (BN=64)
    constexpr int NW_N = BN / 32;           // n-frags per wave
    constexpr int NT = CO / BN;
    constexpr int NCONV = NB * (LIN / BM) * NT;

    __shared__ __align__(16) unsigned short As[2][AGRP * 512];
    __shared__ __align__(16) unsigned short Bs[2][BGRP * 512];

    const int tid = threadIdx.x;
    const int lane = tid & 63;
    const int wv = tid >> 6;

    // bijective XCD-chunk swizzle (m204); NCONV % 8 == 0
    const int orig = blockIdx.x;
    const int q = NCONV >> 3, xcd = orig & 7, o = orig >> 3;
    const int wgid = xcd * q + o;

    const int mg = wgid / NT;               // m-tile (n fastest)
    const int nt = wgid - mg * NT;
    const int b = mg >> 2;                  // LIN/BM == 4
    const int l0 = (mg & 3) * BM;
    const int n0 = nt * BN;

    const int wr = wv >> 1, wc = wv & 1;    // 2x2 wave grid

    const unsigned short* inb = in + (size_t)b * (LIN + 2) * CI;

    f32x4 acc[4][NW_N];
#pragma unroll
    for (int m = 0; m < 4; ++m)
#pragma unroll
        for (int n = 0; n < NW_N; ++n) acc[m][n] = (f32x4){0.f, 0.f, 0.f, 0.f};

    const int lrow = lane >> 2;             // 0..15
    const int lch = lane & 3;               // 16B chunk
    const int fr = lane & 15, kg = lane >> 4;

    const unsigned short* aroot = inb + (size_t)l0 * CI + lch * 8;
    const unsigned short* broot = wg + (size_t)n0 * (3 * CI) + lch * 8;

#define STAGE(c, kb)                                                                      \
    do {                                                                                  \
        const unsigned short* abase = aroot + (kb) * BK;                                  \
        _Pragma("unroll")                                                                 \
        for (int g = wv; g < AGRP; g += 4) {                                              \
            const int sg = g < 9 ? g : 0; /* pad groups reload row 0 (unused in LDS) */   \
            GL2LDS(abase + (size_t)(sg * 16 + lrow) * CI, &As[c][g * 512]);               \
        }                                                                                 \
        const unsigned short* bbase = broot + (kb) * BK;                                  \
        _Pragma("unroll")                                                                 \
        for (int g2 = wv; g2 < BGRP; g2 += 4) {                                           \
            const int t = g2 / GPT, gr = g2 - t * GPT;                                    \
            GL2LDS(bbase + (size_t)(gr * 16 + lrow) * (3 * CI) + (size_t)t * CI,          \
                   &Bs[c][g2 * 512]);                                                     \
        }                                                                                 \
    } while (0)

#define COMPUTE(c)                                                                        \
    do {                                                                                  \
        _Pragma("unroll")                                                                 \
        for (int t = 0; t < 3; ++t) {                                                     \
            bf16x8 aF[4], bF[NW_N];                                                       \
            _Pragma("unroll")                                                             \
            for (int m = 0; m < 4; ++m)                                                   \
                aF[m] = *reinterpret_cast<const bf16x8*>(                                 \
                    &As[c][(t + wr * 64 + m * 16 + fr) * BK + kg * 8]);                   \
            _Pragma("unroll")                                                             \
            for (int n = 0; n < NW_N; ++n)                                                \
                bF[n] = *reinterpret_cast<const bf16x8*>(                                 \
                    &Bs[c][(t * BN + wc * (BN / 2) + n * 16 + fr) * BK + kg * 8]);        \
            _Pragma("unroll")                                                             \
            for (int m = 0; m < 4; ++m)                                                   \
                _Pragma("unroll")                                                         \
                for (int n = 0; n < NW_N; ++n)                                            \
                    acc[m][n] =                                                           \
                        __builtin_amdgcn_mfma_f32_16x16x32_bf16(aF[m], bF[n], acc[m][n],  \
                                                                0, 0, 0);                 \
        }                                                                                 \
    } while (0)

    // ---- 2-deep counted-vmcnt pipeline (R7-exact)
    STAGE(0, 0);
    STAGE(1, 1);
#pragma unroll 1
    for (int kb = 0; kb < KC; ++kb) {
        const int cur = kb & 1;
        if constexpr (BN == 128)
            asm volatile("s_waitcnt vmcnt(9)" ::: "memory");
        else
            asm volatile("s_waitcnt vmcnt(6)" ::: "memory");
        __builtin_amdgcn_sched_barrier(0);
        __builtin_amdgcn_s_barrier();          // all waves' buf[cur] loads landed
        __builtin_amdgcn_sched_barrier(0);
        COMPUTE(cur);
        asm volatile("s_waitcnt lgkmcnt(0)" ::: "memory");  // my ds_reads of buf[cur] done
        __builtin_amdgcn_sched_barrier(0);
        __builtin_amdgcn_s_barrier();          // everyone done reading buf[cur]
        __builtin_amdgcn_sched_barrier(0);
        int nk = kb + 2;
        if (nk >= KC) nk -= KC;                // wrap keeps outstanding count uniform
        STAGE(cur, nk);
    }
#undef STAGE
#undef COMPUTE
    asm volatile("s_waitcnt vmcnt(0)" ::: "memory");        // drain dead wrap-DMA

    // epilogue: bias + ReLU -> bf16; C/D layout col=lane&15, row=(lane>>4)*4+reg
    const int fq = lane >> 4;
    float bv[NW_N];
#pragma unroll
    for (int n = 0; n < NW_N; ++n) bv[n] = bias[n0 + wc * (BN / 2) + n * 16 + fr];
    unsigned short* outb = out + (size_t)b * (LIN + 2) * CO;
#pragma unroll
    for (int m = 0; m < 4; ++m)
#pragma unroll
        for (int qy = 0; qy < 4; ++qy) {
            const int grow = l0 + wr * 64 + m * 16 + fq * 4 + qy + 1;
            unsigned short* orow = outb + (size_t)grow * CO + n0 + wc * (BN / 2) + fr;
#pragma unroll
            for (int n = 0; n < NW_N; ++n) {
                const float v = fmaxf(acc[m][n][qy] + bv[n], 0.f);
                orow[n * 16] = f2bf(v);
            }
        }
}

// ---------------------------------------------------------------- LayerNorm (4 rows per block, in place)

__global__ __launch_bounds__(256) void ln_kernel(unsigned short* __restrict__ h,
                                                 const float* __restrict__ g,
                                                 const float* __restrict__ be) {
    const int row = blockIdx.x * 4 + (threadIdx.x >> 6);
    const int lane = threadIdx.x & 63;
    const int b = row >> 9, l = row & (LIN - 1);
    unsigned short* hr = h + ((size_t)b * (LIN + 2) + l + 1) * DM;
    float v[6];
    float s = 0.f;
#pragma unroll
    for (int j = 0; j < 6; ++j) { v[j] = bf2f(hr[lane + 64 * j]); s += v[j]; }
    s = wred(s);
    const float mean = s * (1.f / DM);
    float vs = 0.f;
#pragma unroll
    for (int j = 0; j < 6; ++j) { const float d = v[j] - mean; vs += d * d; }
    vs = wred(vs);
    const float rstd = rsqrtf(vs * (1.f / DM) + LN_EPS);
#pragma unroll
    for (int j = 0; j < 6; ++j) {
        const int c = lane + 64 * j;
        hr[c] = f2bf((v[j] - mean) * rstd * g[c] + be[c]);
    }
}

// ---------------------------------------------------------------- LayerNorm + linear(384->1), 4 rows/block

__global__ __launch_bounds__(256) void ln_linear_kernel(const unsigned short* __restrict__ h,
                                                        const float* __restrict__ g,
                                                        const float* __restrict__ be,
                                                        const float* __restrict__ wl,
                                                        const float* __restrict__ bl,
                                                        float* __restrict__ dur) {
    const int row = blockIdx.x * 4 + (threadIdx.x >> 6);
    const int lane = threadIdx.x & 63;
    const int b = row >> 9, l = row & (LIN - 1);
    const unsigned short* hr = h + ((size_t)b * (LIN + 2) + l + 1) * DM;
    float v[6];
    float s = 0.f;
#pragma unroll
    for (int j = 0; j < 6; ++j) { v[j] = bf2f(hr[lane + 64 * j]); s += v[j]; }
    s = wred(s);
    const float mean = s * (1.f / DM);
    float vs = 0.f;
#pragma unroll
    for (int j = 0; j < 6; ++j) { const float d = v[j] - mean; vs += d * d; }
    vs = wred(vs);
    const float rstd = rsqrtf(vs * (1.f / DM) + LN_EPS);
    float dot = 0.f;
#pragma unroll
    for (int j = 0; j < 6; ++j) {
        const int c = lane + 64 * j;
        dot += ((v[j] - mean) * rstd * g[c] + be[c]) * wl[c];
    }
    dot = wred(dot);
    if (lane == 0) dur[row] = dot + bl[0];
}

// ---------------------------------------------------------------- launch

extern "C" void kernel_launch(void* const* d_in, const int* in_sizes, int n_in,
                              void* d_out, int out_size, void* d_ws, size_t ws_size,
                              hipStream_t stream) {
    const float* x   = (const float*)d_in[0];
    const int*   tgt = (const int*)d_in[1];
    const float* w1  = (const float*)d_in[3];
    const float* b1  = (const float*)d_in[4];
    const float* w2  = (const float*)d_in[5];
    const float* b2  = (const float*)d_in[6];
    const float* g1  = (const float*)d_in[7];
    const float* be1 = (const float*)d_in[8];
    const float* w3  = (const float*)d_in[9];
    const float* b3  = (const float*)d_in[10];
    const float* w4  = (const float*)d_in[11];
    const float* b4  = (const float*)d_in[12];
    const float* g2  = (const float*)d_in[13];
    const float* be2 = (const float*)d_in[14];
    const float* wl  = (const float*)d_in[15];
    const float* bl  = (const float*)d_in[16];

    float* out = (float*)d_out;                         // (16, 4096, 384) f32
    float* dur = out + (size_t)NB * MELMAX * DM;        // (16, 512) f32

    unsigned short* ws = (unsigned short*)d_ws;
    unsigned short* xb   = ws;                                 // (16, 514, 384)  also conv4 out
    unsigned short* hbig = xb + (size_t)NB * (LIN + 2) * DM;   // (16, 514, 1536) conv1/conv3 out
    unsigned short* h2b  = hbig + (size_t)NB * (LIN + 2) * DC; // (16, 514, 384)  conv2 out
    unsigned short* wg1  = h2b + (size_t)NB * (LIN + 2) * DM;  // (1536, 1152)
    unsigned short* wg2  = wg1 + (size_t)DC * 3 * DM;          // (384, 4608)
    unsigned short* wg3  = wg2 + (size_t)DM * 3 * DC;          // (1536, 1152)
    unsigned short* wg4  = wg3 + (size_t)DC * 3 * DM;          // (384, 4608)
    int* cum = (int*)(wg4 + (size_t)DM * 3 * DC);              // (16, 512)

    // ---- prep (zpad + cast_x + wcast + cumsum, one launch)
    prep_kernel<<<PREP_TOTAL, 256, 0, stream>>>(x, xb, hbig, h2b, w1, w2, w3, w4,
                                                wg1, wg2, wg3, wg4, tgt, cum);

    // ---- output 0: length regulate (after prep: cum ready)
    gather_kernel<<<(NB * MELMAX) / 4, 256, 0, stream>>>(x, cum, out);

    // ---- output 1: duration predictor (bf16 MFMA convs, R7-exact counted-vmcnt)
    conv_mfma_kernel<DM, DC, 128><<<NB * (LIN / 128) * (DC / 128), 256, 0, stream>>>(xb, wg1, b1, hbig);
    conv_mfma_kernel<DC, DM, 64><<<NB * (LIN / 128) * (DM / 64), 256, 0, stream>>>(hbig, wg2, b2, h2b);
    ln_kernel<<<NB * LIN / 4, 256, 0, stream>>>(h2b, g1, be1);
    conv_mfma_kernel<DM, DC, 128><<<NB * (LIN / 128) * (DC / 128), 256, 0, stream>>>(h2b, wg3, b3, hbig);
    conv_mfma_kernel<DC, DM, 64><<<NB * (LIN / 128) * (DM / 64), 256, 0, stream>>>(hbig, wg4, b4, xb);
    ln_linear_kernel<<<NB * LIN / 4, 256, 0, stream>>>(xb, g2, be2, wl, bl, dur);
}

// Round 18
// 216.794 us; speedup vs baseline: 1.0188x; 1.0188x over previous
//
#include <hip/hip_runtime.h>
#include <hip/hip_bf16.h>
#include <cstddef>
#include <cstdint>

#define NB 16
#define LIN 512
#define DM 384
#define DC 1536
#define MELMAX 4096
#define LN_EPS 1e-5f

typedef __bf16 bf16x8 __attribute__((ext_vector_type(8)));
typedef float f32x4 __attribute__((ext_vector_type(4)));

#define GL2LDS(gp, lp)                                                                \
    __builtin_amdgcn_global_load_lds((const __attribute__((address_space(1))) void*)(gp), \
                                     (__attribute__((address_space(3))) void*)(lp), 16, 0, 0)

__device__ __forceinline__ float wred(float v) {
#pragma unroll
    for (int m = 32; m >= 1; m >>= 1) v += __shfl_xor(v, m, 64);
    return v;
}

__device__ __forceinline__ unsigned short f2bf(float f) {
    __hip_bfloat16 h = __float2bfloat16(f);
    return *reinterpret_cast<unsigned short*>(&h);
}

__device__ __forceinline__ float bf2f(unsigned short u) {
    return __uint_as_float(((unsigned)u) << 16);
}

// ---------------------------------------------------------------- length-regulate gather (standalone)

__global__ __launch_bounds__(256) void gather_kernel(const float* __restrict__ x,
                                                     const int* __restrict__ cum,
                                                     float* __restrict__ out) {
    const int wid = (blockIdx.x * 256 + threadIdx.x) >> 6;
    const int lane = threadIdx.x & 63;
    const int b = wid >> 12;
    const int t = wid & (MELMAX - 1);
    const int* c = cum + b * LIN;
    const int total = c[LIN - 1];
    float4* orow = reinterpret_cast<float4*>(out + ((size_t)b * MELMAX + t) * DM);
    if (t < total) {
        int lo = 0, hi = LIN;
        while (lo < hi) { int mid = (lo + hi) >> 1; if (c[mid] > t) hi = mid; else lo = mid + 1; }
        const int idx = lo < (LIN - 1) ? lo : (LIN - 1);
        const float4* xrow = reinterpret_cast<const float4*>(x + ((size_t)b * LIN + idx) * DM);
#pragma unroll
        for (int j = 0; j < 2; ++j) {
            const int p = lane + 64 * j;
            if (p < DM / 4) orow[p] = xrow[p];
        }
    } else {
        const float4 z = make_float4(0.f, 0.f, 0.f, 0.f);
#pragma unroll
        for (int j = 0; j < 2; ++j) {
            const int p = lane + 64 * j;
            if (p < DM / 4) orow[p] = z;
        }
    }
}

// ---------------------------------------------------------------- fused prep: zpad + cast_x + wcast + cumsum

#define ZPAD_BLKS 96
#define CASTX_BLKS 3072   // NB*LIN*DM/4/256
#define WCAST_BLKS 288    // DC*DM/8/256 per matrix
#define PREP_TOTAL (ZPAD_BLKS + CASTX_BLKS + 4 * WCAST_BLKS + NB)

__global__ void prep_kernel(const float* __restrict__ x, unsigned short* __restrict__ xb,
                            unsigned short* __restrict__ hbig, unsigned short* __restrict__ h2b,
                            const float* __restrict__ w1, const float* __restrict__ w2,
                            const float* __restrict__ w3, const float* __restrict__ w4,
                            unsigned short* __restrict__ o1, unsigned short* __restrict__ o2,
                            unsigned short* __restrict__ o3, unsigned short* __restrict__ o4,
                            const int* __restrict__ tgt, int* __restrict__ cum) {
    const int bid = blockIdx.x, tid = threadIdx.x;
    if (bid < ZPAD_BLKS) {
        const int buf = bid >> 5, rem = bid & 31;
        const int b = rem >> 1, row = (rem & 1) ? (LIN + 1) : 0;
        unsigned short* p = buf == 0 ? xb : (buf == 1 ? hbig : h2b);
        const int rl = buf == 1 ? DC : DM;
        unsigned short* base = p + ((size_t)b * (LIN + 2) + row) * rl;
        for (int c = tid; c < rl; c += 256) base[c] = 0;
        return;
    }
    if (bid < ZPAD_BLKS + CASTX_BLKS) {
        const int idx = (bid - ZPAD_BLKS) * 256 + tid;
        const float4 v = reinterpret_cast<const float4*>(x)[idx];
        const int e = idx * 4;
        const int b = e / (LIN * DM);
        const int rem = e - b * (LIN * DM);
        const int l = rem / DM;
        const int c = rem - l * DM;
        ushort4 o;
        o.x = f2bf(v.x); o.y = f2bf(v.y); o.z = f2bf(v.z); o.w = f2bf(v.w);
        *reinterpret_cast<ushort4*>(xb + ((size_t)b * (LIN + 2) + l + 1) * DM + c) = o;
        return;
    }
    if (bid < ZPAD_BLKS + CASTX_BLKS + 4 * WCAST_BLKS) {
        const int j = bid - ZPAD_BLKS - CASTX_BLKS;
        const int which = j / WCAST_BLKS;
        const int idx = (j - which * WCAST_BLKS) * 256 + tid;   // (co, ci-octet)
        const float* w = which == 0 ? w1 : which == 1 ? w2 : which == 2 ? w3 : w4;
        unsigned short* gg = which == 0 ? o1 : which == 1 ? o2 : which == 2 ? o3 : o4;
        const int CI = (which == 0 || which == 2) ? DM : DC;
        const int OCT = CI / 8;
        const int co = idx / OCT, ci0 = (idx - co * OCT) * 8;
        const float4* p4 = reinterpret_cast<const float4*>(w + (size_t)(co * CI + ci0) * 3);
        float v[24];
#pragma unroll
        for (int q = 0; q < 6; ++q) *reinterpret_cast<float4*>(&v[q * 4]) = p4[q];
        unsigned short tmp[3][8];
#pragma unroll
        for (int e = 0; e < 24; ++e) tmp[e % 3][e / 3] = f2bf(v[e]);
        unsigned short* ob = gg + (size_t)co * (3 * CI) + ci0;
#pragma unroll
        for (int t = 0; t < 3; ++t)
            *reinterpret_cast<uint4*>(ob + (size_t)t * CI) = *reinterpret_cast<const uint4*>(tmp[t]);
        return;
    }
    // ---- cumsum: one block per batch
    {
        const int b = bid - (ZPAD_BLKS + CASTX_BLKS + 4 * WCAST_BLKS);
        __shared__ int s[LIN];
        s[tid] = tgt[b * LIN + tid];
        s[tid + 256] = tgt[b * LIN + tid + 256];
        __syncthreads();
        for (int off = 1; off < LIN; off <<= 1) {
            int v0 = (tid >= off) ? s[tid - off] : 0;
            int v1 = (tid + 256 >= off) ? s[tid + 256 - off] : 0;
            __syncthreads();
            s[tid] += v0;
            s[tid + 256] += v1;
            __syncthreads();
        }
        cum[b * LIN + tid] = s[tid];
        cum[b * LIN + tid + 256] = s[tid + 256];
    }
}

// ---------------------------------------------------------------- conv1/3: 256x256 8-phase (race-fixed)
// Fixes vs R16: (1) LDB half = nh (cc = nh*128 + wcN*32 + nf*16 + fr) so B-half0's
// last reader is ph1 and half1's is ph3 — staging at ph2/ph4 is behind the last
// reader's lgkm+barrier; (2) ph3 stages A(s1,H1,k1) — current-slot A is NEVER
// overwritten mid-iteration (ph4's A re-read is safe); (3) epilogue/bias col
// mapping matches the new LDB; (4) prologue stages {A(0,k0)x2, B(0,k0)x2,
// B(1,k1)x2} + vmcnt(4); (5) per-iter wait = vmcnt(2) at ph4 (retires this
// iter's A-stages and prev iter's B-stages; ledger verified over m-1/m/m+1).

__global__ __launch_bounds__(512, 2) void conv8_kernel(const unsigned short* __restrict__ in,
                                                       const unsigned short* __restrict__ wg,
                                                       const float* __restrict__ bias,
                                                       unsigned short* __restrict__ out) {
    constexpr int NKT = 18;                 // 1152 / 64
    __shared__ __align__(16) unsigned short smem[65536];   // 128 KB

    const int tid = threadIdx.x, lane = tid & 63, wv = tid >> 6;
    const int wrM = wv >> 2, wcN = wv & 3;  // 2M x 4N wave grid

    // bijective XCD swizzle over 192 blocks (= 8 * 24)
    const int orig = blockIdx.x;
    const int wgid = (orig & 7) * 24 + (orig >> 3);
    const int mt = wgid / 6, ng = wgid - mt * 6;
    const int b = mt >> 1, tm = mt & 1;
    const int n0 = ng * 256;

    const unsigned short* inb = in + ((size_t)b * (LIN + 2) + (size_t)tm * 256) * DM;

    const int fr = lane & 15, kg = lane >> 4;

    f32x4 acc[8][4];
#pragma unroll
    for (int i = 0; i < 8; ++i)
#pragma unroll
        for (int j = 0; j < 4; ++j) acc[i][j] = (f32x4){0.f, 0.f, 0.f, 0.f};

#define STG_A(s, H, kt)                                                                   \
    do {                                                                                  \
        const int t_ = (kt) / 6, kc_ = (kt) - t_ * 6;                                     \
        _Pragma("unroll")                                                                 \
        for (int j = 0; j < 2; ++j) {                                                     \
            const int rr = (tid >> 3) + j * 64;                                           \
            const int e = ((tid & 7) * 8) ^ ((rr & 4) << 2);                              \
            GL2LDS(inb + (size_t)(t_ + (H)*128 + rr) * DM + kc_ * 64 + e,                 \
                   smem + (s)*32768 + (H)*8192 + tid * 8 + j * 4096);                     \
        }                                                                                 \
    } while (0)

#define STG_B(s, H, kt)                                                                   \
    do {                                                                                  \
        const int t_ = (kt) / 6, kc_ = (kt) - t_ * 6;                                     \
        _Pragma("unroll")                                                                 \
        for (int j = 0; j < 2; ++j) {                                                     \
            const int rr = (tid >> 3) + j * 64;                                           \
            const int e = ((tid & 7) * 8) ^ ((rr & 4) << 2);                              \
            GL2LDS(wg + (size_t)(n0 + (H)*128 + rr) * 1152 + t_ * 384 + kc_ * 64 + e,     \
                   smem + (s)*32768 + 16384 + (H)*8192 + tid * 8 + j * 4096);             \
        }                                                                                 \
    } while (0)

#define LDA(mh, s)                                                                        \
    do {                                                                                  \
        _Pragma("unroll")                                                                 \
        for (int mf = 0; mf < 4; ++mf)                                                    \
            _Pragma("unroll")                                                             \
            for (int kh = 0; kh < 2; ++kh) {                                              \
                const int rr = (mh)*64 + mf * 16 + fr;                                    \
                const int ke = (kh * 32 + kg * 8) ^ ((rr & 4) << 2);                      \
                aF[mf][kh] = *reinterpret_cast<const bf16x8*>(                            \
                    smem + (s)*32768 + wrM * 8192 + rr * 64 + ke);                        \
            }                                                                             \
    } while (0)

#define LDB(nh, s)                                                                        \
    do {                                                                                  \
        _Pragma("unroll")                                                                 \
        for (int nf = 0; nf < 2; ++nf)                                                    \
            _Pragma("unroll")                                                             \
            for (int kh = 0; kh < 2; ++kh) {                                              \
                const int rr = wcN * 32 + nf * 16 + fr;                                   \
                const int ke = (kh * 32 + kg * 8) ^ ((rr & 4) << 2);                      \
                bF[nf][kh] = *reinterpret_cast<const bf16x8*>(                            \
                    smem + (s)*32768 + 16384 + (nh)*8192 + rr * 64 + ke);                 \
            }                                                                             \
    } while (0)

#define MMA(mh, nh)                                                                       \
    do {                                                                                  \
        _Pragma("unroll")                                                                 \
        for (int mf = 0; mf < 4; ++mf)                                                    \
            _Pragma("unroll")                                                             \
            for (int nf = 0; nf < 2; ++nf)                                                \
                _Pragma("unroll")                                                         \
                for (int kh = 0; kh < 2; ++kh)                                            \
                    acc[(mh)*4 + mf][(nh)*2 + nf] = __builtin_amdgcn_mfma_f32_16x16x32_bf16( \
                        aF[mf][kh], bF[nf][kh], acc[(mh)*4 + mf][(nh)*2 + nf], 0, 0, 0);  \
    } while (0)

    // ---- prologue: slot0 complete (A+B of k0) + B(1,k1); 4 loads left in flight
    STG_A(0, 0, 0); STG_A(0, 1, 0); STG_B(0, 0, 0); STG_B(0, 1, 0);
    STG_B(1, 0, 1); STG_B(1, 1, 1);
    asm volatile("s_waitcnt vmcnt(4)" ::: "memory");
    asm volatile("s_barrier" ::: "memory");

#pragma unroll 1
    for (int m = 0; m < NKT; ++m) {
        const int s = m & 1, s1 = s ^ 1;
        int k1 = m + 1; if (k1 >= NKT) k1 -= NKT;
        int k2 = m + 2; if (k2 >= NKT) k2 -= NKT;
        bf16x8 aF[4][2], bF[2][2];
        // ph1: Q(0,0) — read A rows 0-63 (wave half) + B half0
        LDA(0, s); LDB(0, s);
        STG_A(s1, 0, k1);
        asm volatile("s_barrier" ::: "memory");
        asm volatile("s_waitcnt lgkmcnt(0)" ::: "memory");
        __builtin_amdgcn_s_setprio(1); MMA(0, 0); __builtin_amdgcn_s_setprio(0);
        asm volatile("s_barrier" ::: "memory");
        // ph2: Q(1,0) — read A rows 64-127, reuse bF (half0)
        LDA(1, s);
        STG_B(s, 0, k2);                       // B half0 last read at ph1 ✓
        asm volatile("s_barrier" ::: "memory");
        asm volatile("s_waitcnt lgkmcnt(0)" ::: "memory");
        __builtin_amdgcn_s_setprio(1); MMA(1, 0); __builtin_amdgcn_s_setprio(0);
        asm volatile("s_barrier" ::: "memory");
        // ph3: Q(1,1) — read B half1, reuse aF (rows 64-127)
        LDB(1, s);
        STG_A(s1, 1, k1);                      // other slot ✓
        asm volatile("s_barrier" ::: "memory");
        asm volatile("s_waitcnt lgkmcnt(0)" ::: "memory");
        __builtin_amdgcn_s_setprio(1); MMA(1, 1); __builtin_amdgcn_s_setprio(0);
        asm volatile("s_barrier" ::: "memory");
        // ph4: Q(0,1) — re-read A rows 0-63 (never staged-over this iter), reuse bF (half1)
        LDA(0, s);
        STG_B(s, 1, k2);                       // B half1 last read at ph3 ✓
        asm volatile("s_barrier" ::: "memory");
        asm volatile("s_waitcnt lgkmcnt(0)" ::: "memory");
        __builtin_amdgcn_s_setprio(1); MMA(0, 1); __builtin_amdgcn_s_setprio(0);
        asm volatile("s_waitcnt vmcnt(2)" ::: "memory");   // retire A-stages (this iter) + B-stages (prev iter)
        asm volatile("s_barrier" ::: "memory");
    }
#undef STG_A
#undef STG_B
#undef LDA
#undef LDB
#undef MMA
    asm volatile("s_waitcnt vmcnt(0)" ::: "memory");   // drain dead wrap-DMA

    // epilogue: bias + ReLU -> bf16; C/D layout col=lane&15, row=(lane>>4)*4+reg
    const int fq = lane >> 4;
    float bv[4];
#pragma unroll
    for (int nh = 0; nh < 2; ++nh)
#pragma unroll
        for (int nf = 0; nf < 2; ++nf)
            bv[nh * 2 + nf] = bias[n0 + nh * 128 + wcN * 32 + nf * 16 + fr];
    unsigned short* outb = out + ((size_t)b * (LIN + 2) + (size_t)tm * 256 + 1) * DC;
#pragma unroll
    for (int mh = 0; mh < 2; ++mh)
#pragma unroll
        for (int mf = 0; mf < 4; ++mf)
#pragma unroll
            for (int qy = 0; qy < 4; ++qy) {
                const int r = wrM * 128 + mh * 64 + mf * 16 + fq * 4 + qy;
                unsigned short* orow = outb + (size_t)r * DC + n0;
#pragma unroll
                for (int nh = 0; nh < 2; ++nh)
#pragma unroll
                    for (int nf = 0; nf < 2; ++nf) {
                        const float v = fmaxf(acc[mh * 4 + mf][nh * 2 + nf][qy] + bv[nh * 2 + nf], 0.f);
                        orow[nh * 128 + wcN * 32 + nf * 16 + fr] = f2bf(v);
                    }
            }
}

// ---------------------------------------------------------------- conv2/4: R7-exact counted-vmcnt kernel (BN=64)

template <int CI, int CO, int BN>
__global__ __launch_bounds__(256, 2) void conv_mfma_kernel(const unsigned short* __restrict__ in,
                                                           const unsigned short* __restrict__ wg,
                                                           const float* __restrict__ bias,
                                                           unsigned short* __restrict__ out) {
    constexpr int BM = 128, BK = 32;
    constexpr int KC = CI / BK;
    constexpr int AGRP = 12;
    constexpr int GPT = BN / 16;
    constexpr int BGRP = 3 * GPT;
    constexpr int NW_N = BN / 32;
    constexpr int NT = CO / BN;
    constexpr int NCONV = NB * (LIN / BM) * NT;

    __shared__ __align__(16) unsigned short As[2][AGRP * 512];
    __shared__ __align__(16) unsigned short Bs[2][BGRP * 512];

    const int tid = threadIdx.x;
    const int lane = tid & 63;
    const int wv = tid >> 6;

    const int orig = blockIdx.x;
    const int q = NCONV >> 3, xcd = orig & 7, o = orig >> 3;
    const int wgid = xcd * q + o;

    const int mg = wgid / NT;
    const int nt = wgid - mg * NT;
    const int b = mg >> 2;
    const int l0 = (mg & 3) * BM;
    const int n0 = nt * BN;

    const int wr = wv >> 1, wc = wv & 1;

    const unsigned short* inb = in + (size_t)b * (LIN + 2) * CI;

    f32x4 acc[4][NW_N];
#pragma unroll
    for (int m = 0; m < 4; ++m)
#pragma unroll
        for (int n = 0; n < NW_N; ++n) acc[m][n] = (f32x4){0.f, 0.f, 0.f, 0.f};

    const int lrow = lane >> 2;
    const int lch = lane & 3;
    const int fr = lane & 15, kg = lane >> 4;

    const unsigned short* aroot = inb + (size_t)l0 * CI + lch * 8;
    const unsigned short* broot = wg + (size_t)n0 * (3 * CI) + lch * 8;

#define STAGE(c, kb)                                                                      \
    do {                                                                                  \
        const unsigned short* abase = aroot + (kb) * BK;                                  \
        _Pragma("unroll")                                                                 \
        for (int g = wv; g < AGRP; g += 4) {                                              \
            const int sg = g < 9 ? g : 0;                                                 \
            GL2LDS(abase + (size_t)(sg * 16 + lrow) * CI, &As[c][g * 512]);               \
        }                                                                                 \
        const unsigned short* bbase = broot + (kb) * BK;                                  \
        _Pragma("unroll")                                                                 \
        for (int g2 = wv; g2 < BGRP; g2 += 4) {                                           \
            const int t = g2 / GPT, gr = g2 - t * GPT;                                    \
            GL2LDS(bbase + (size_t)(gr * 16 + lrow) * (3 * CI) + (size_t)t * CI,          \
                   &Bs[c][g2 * 512]);                                                     \
        }                                                                                 \
    } while (0)

#define COMPUTE(c)                                                                        \
    do {                                                                                  \
        _Pragma("unroll")                                                                 \
        for (int t = 0; t < 3; ++t) {                                                     \
            bf16x8 aF[4], bF[NW_N];                                                       \
            _Pragma("unroll")                                                             \
            for (int m = 0; m < 4; ++m)                                                   \
                aF[m] = *reinterpret_cast<const bf16x8*>(                                 \
                    &As[c][(t + wr * 64 + m * 16 + fr) * BK + kg * 8]);                   \
            _Pragma("unroll")                                                             \
            for (int n = 0; n < NW_N; ++n)                                                \
                bF[n] = *reinterpret_cast<const bf16x8*>(                                 \
                    &Bs[c][(t * BN + wc * (BN / 2) + n * 16 + fr) * BK + kg * 8]);        \
            _Pragma("unroll")                                                             \
            for (int m = 0; m < 4; ++m)                                                   \
                _Pragma("unroll")                                                         \
                for (int n = 0; n < NW_N; ++n)                                            \
                    acc[m][n] =                                                           \
                        __builtin_amdgcn_mfma_f32_16x16x32_bf16(aF[m], bF[n], acc[m][n],  \
                                                                0, 0, 0);                 \
        }                                                                                 \
    } while (0)

    STAGE(0, 0);
    STAGE(1, 1);
#pragma unroll 1
    for (int kb = 0; kb < KC; ++kb) {
        const int cur = kb & 1;
        if constexpr (BN == 128)
            asm volatile("s_waitcnt vmcnt(9)" ::: "memory");
        else
            asm volatile("s_waitcnt vmcnt(6)" ::: "memory");
        __builtin_amdgcn_sched_barrier(0);
        __builtin_amdgcn_s_barrier();
        __builtin_amdgcn_sched_barrier(0);
        COMPUTE(cur);
        asm volatile("s_waitcnt lgkmcnt(0)" ::: "memory");
        __builtin_amdgcn_sched_barrier(0);
        __builtin_amdgcn_s_barrier();
        __builtin_amdgcn_sched_barrier(0);
        int nk = kb + 2;
        if (nk >= KC) nk -= KC;
        STAGE(cur, nk);
    }
#undef STAGE
#undef COMPUTE
    asm volatile("s_waitcnt vmcnt(0)" ::: "memory");

    const int fq = lane >> 4;
    float bv[NW_N];
#pragma unroll
    for (int n = 0; n < NW_N; ++n) bv[n] = bias[n0 + wc * (BN / 2) + n * 16 + fr];
    unsigned short* outb = out + (size_t)b * (LIN + 2) * CO;
#pragma unroll
    for (int m = 0; m < 4; ++m)
#pragma unroll
        for (int qy = 0; qy < 4; ++qy) {
            const int grow = l0 + wr * 64 + m * 16 + fq * 4 + qy + 1;
            unsigned short* orow = outb + (size_t)grow * CO + n0 + wc * (BN / 2) + fr;
#pragma unroll
            for (int n = 0; n < NW_N; ++n) {
                const float v = fmaxf(acc[m][n][qy] + bv[n], 0.f);
                orow[n * 16] = f2bf(v);
            }
        }
}

// ---------------------------------------------------------------- LayerNorm (4 rows per block, in place)

__global__ __launch_bounds__(256) void ln_kernel(unsigned short* __restrict__ h,
                                                 const float* __restrict__ g,
                                                 const float* __restrict__ be) {
    const int row = blockIdx.x * 4 + (threadIdx.x >> 6);
    const int lane = threadIdx.x & 63;
    const int b = row >> 9, l = row & (LIN - 1);
    unsigned short* hr = h + ((size_t)b * (LIN + 2) + l + 1) * DM;
    float v[6];
    float s = 0.f;
#pragma unroll
    for (int j = 0; j < 6; ++j) { v[j] = bf2f(hr[lane + 64 * j]); s += v[j]; }
    s = wred(s);
    const float mean = s * (1.f / DM);
    float vs = 0.f;
#pragma unroll
    for (int j = 0; j < 6; ++j) { const float d = v[j] - mean; vs += d * d; }
    vs = wred(vs);
    const float rstd = rsqrtf(vs * (1.f / DM) + LN_EPS);
#pragma unroll
    for (int j = 0; j < 6; ++j) {
        const int c = lane + 64 * j;
        hr[c] = f2bf((v[j] - mean) * rstd * g[c] + be[c]);
    }
}

// ---------------------------------------------------------------- LayerNorm + linear(384->1), 4 rows/block

__global__ __launch_bounds__(256) void ln_linear_kernel(const unsigned short* __restrict__ h,
                                                        const float* __restrict__ g,
                                                        const float* __restrict__ be,
                                                        const float* __restrict__ wl,
                                                        const float* __restrict__ bl,
                                                        float* __restrict__ dur) {
    const int row = blockIdx.x * 4 + (threadIdx.x >> 6);
    const int lane = threadIdx.x & 63;
    const int b = row >> 9, l = row & (LIN - 1);
    const unsigned short* hr = h + ((size_t)b * (LIN + 2) + l + 1) * DM;
    float v[6];
    float s = 0.f;
#pragma unroll
    for (int j = 0; j < 6; ++j) { v[j] = bf2f(hr[lane + 64 * j]); s += v[j]; }
    s = wred(s);
    const float mean = s * (1.f / DM);
    float vs = 0.f;
#pragma unroll
    for (int j = 0; j < 6; ++j) { const float d = v[j] - mean; vs += d * d; }
    vs = wred(vs);
    const float rstd = rsqrtf(vs * (1.f / DM) + LN_EPS);
    float dot = 0.f;
#pragma unroll
    for (int j = 0; j < 6; ++j) {
        const int c = lane + 64 * j;
        dot += ((v[j] - mean) * rstd * g[c] + be[c]) * wl[c];
    }
    dot = wred(dot);
    if (lane == 0) dur[row] = dot + bl[0];
}

// ---------------------------------------------------------------- launch

extern "C" void kernel_launch(void* const* d_in, const int* in_sizes, int n_in,
                              void* d_out, int out_size, void* d_ws, size_t ws_size,
                              hipStream_t stream) {
    const float* x   = (const float*)d_in[0];
    const int*   tgt = (const int*)d_in[1];
    const float* w1  = (const float*)d_in[3];
    const float* b1  = (const float*)d_in[4];
    const float* w2  = (const float*)d_in[5];
    const float* b2  = (const float*)d_in[6];
    const float* g1  = (const float*)d_in[7];
    const float* be1 = (const float*)d_in[8];
    const float* w3  = (const float*)d_in[9];
    const float* b3  = (const float*)d_in[10];
    const float* w4  = (const float*)d_in[11];
    const float* b4  = (const float*)d_in[12];
    const float* g2  = (const float*)d_in[13];
    const float* be2 = (const float*)d_in[14];
    const float* wl  = (const float*)d_in[15];
    const float* bl  = (const float*)d_in[16];

    float* out = (float*)d_out;                         // (16, 4096, 384) f32
    float* dur = out + (size_t)NB * MELMAX * DM;        // (16, 512) f32

    unsigned short* ws = (unsigned short*)d_ws;
    unsigned short* xb   = ws;                                 // (16, 514, 384)  also conv4 out
    unsigned short* hbig = xb + (size_t)NB * (LIN + 2) * DM;   // (16, 514, 1536) conv1/conv3 out
    unsigned short* h2b  = hbig + (size_t)NB * (LIN + 2) * DC; // (16, 514, 384)  conv2 out
    unsigned short* wg1  = h2b + (size_t)NB * (LIN + 2) * DM;  // (1536, 1152)
    unsigned short* wg2  = wg1 + (size_t)DC * 3 * DM;          // (384, 4608)
    unsigned short* wg3  = wg2 + (size_t)DM * 3 * DC;          // (1536, 1152)
    unsigned short* wg4  = wg3 + (size_t)DC * 3 * DM;          // (384, 4608)
    int* cum = (int*)(wg4 + (size_t)DM * 3 * DC);              // (16, 512)

    // ---- prep (zpad + cast_x + wcast + cumsum, one launch)
    prep_kernel<<<PREP_TOTAL, 256, 0, stream>>>(x, xb, hbig, h2b, w1, w2, w3, w4,
                                                wg1, wg2, wg3, wg4, tgt, cum);

    // ---- output 0: length regulate
    gather_kernel<<<(NB * MELMAX) / 4, 256, 0, stream>>>(x, cum, out);

    // ---- output 1: duration predictor
    // conv1/3: race-fixed 256^2 8-phase kernel; conv2/4: R7 counted-vmcnt
    conv8_kernel<<<NB * 2 * (DC / 256), 512, 0, stream>>>(xb, wg1, b1, hbig);
    conv_mfma_kernel<DC, DM, 64><<<NB * (LIN / 128) * (DM / 64), 256, 0, stream>>>(hbig, wg2, b2, h2b);
    ln_kernel<<<NB * LIN / 4, 256, 0, stream>>>(h2b, g1, be1);
    conv8_kernel<<<NB * 2 * (DC / 256), 512, 0, stream>>>(h2b, wg3, b3, hbig);
    conv_mfma_kernel<DC, DM, 64><<<NB * (LIN / 128) * (DM / 64), 256, 0, stream>>>(hbig, wg4, b4, xb);
    ln_linear_kernel<<<NB * LIN / 4, 256, 0, stream>>>(xb, g2, be2, wl, bl, dur);
}

// Round 19
// 203.935 us; speedup vs baseline: 1.0830x; 1.0631x over previous
//
#include <hip/hip_runtime.h>
#include <hip/hip_bf16.h>
#include <cstddef>
#include <cstdint>

#define NB 16
#define LIN 512
#define DM 384
#define DC 1536
#define MELMAX 4096
#define LN_EPS 1e-5f

typedef __bf16 bf16x8 __attribute__((ext_vector_type(8)));
typedef float f32x4 __attribute__((ext_vector_type(4)));

#define GL2LDS(gp, lp)                                                                \
    __builtin_amdgcn_global_load_lds((const __attribute__((address_space(1))) void*)(gp), \
                                     (__attribute__((address_space(3))) void*)(lp), 16, 0, 0)

__device__ __forceinline__ float wred(float v) {
#pragma unroll
    for (int m = 32; m >= 1; m >>= 1) v += __shfl_xor(v, m, 64);
    return v;
}

__device__ __forceinline__ unsigned short f2bf(float f) {
    __hip_bfloat16 h = __float2bfloat16(f);
    return *reinterpret_cast<unsigned short*>(&h);
}

__device__ __forceinline__ float bf2f(unsigned short u) {
    return __uint_as_float(((unsigned)u) << 16);
}

// ---------------------------------------------------------------- length-regulate gather (standalone)

__global__ __launch_bounds__(256) void gather_kernel(const float* __restrict__ x,
                                                     const int* __restrict__ cum,
                                                     float* __restrict__ out) {
    const int wid = (blockIdx.x * 256 + threadIdx.x) >> 6;
    const int lane = threadIdx.x & 63;
    const int b = wid >> 12;
    const int t = wid & (MELMAX - 1);
    const int* c = cum + b * LIN;
    const int total = c[LIN - 1];
    float4* orow = reinterpret_cast<float4*>(out + ((size_t)b * MELMAX + t) * DM);
    if (t < total) {
        int lo = 0, hi = LIN;
        while (lo < hi) { int mid = (lo + hi) >> 1; if (c[mid] > t) hi = mid; else lo = mid + 1; }
        const int idx = lo < (LIN - 1) ? lo : (LIN - 1);
        const float4* xrow = reinterpret_cast<const float4*>(x + ((size_t)b * LIN + idx) * DM);
#pragma unroll
        for (int j = 0; j < 2; ++j) {
            const int p = lane + 64 * j;
            if (p < DM / 4) orow[p] = xrow[p];
        }
    } else {
        const float4 z = make_float4(0.f, 0.f, 0.f, 0.f);
#pragma unroll
        for (int j = 0; j < 2; ++j) {
            const int p = lane + 64 * j;
            if (p < DM / 4) orow[p] = z;
        }
    }
}

// ---------------------------------------------------------------- fused prep: zpad + cast_x + wcast + cumsum

#define ZPAD_BLKS 96
#define CASTX_BLKS 3072   // NB*LIN*DM/4/256
#define WCAST_BLKS 288    // DC*DM/8/256 per matrix
#define PREP_TOTAL (ZPAD_BLKS + CASTX_BLKS + 4 * WCAST_BLKS + NB)

__global__ void prep_kernel(const float* __restrict__ x, unsigned short* __restrict__ xb,
                            unsigned short* __restrict__ hbig, unsigned short* __restrict__ h2b,
                            const float* __restrict__ w1, const float* __restrict__ w2,
                            const float* __restrict__ w3, const float* __restrict__ w4,
                            unsigned short* __restrict__ o1, unsigned short* __restrict__ o2,
                            unsigned short* __restrict__ o3, unsigned short* __restrict__ o4,
                            const int* __restrict__ tgt, int* __restrict__ cum) {
    const int bid = blockIdx.x, tid = threadIdx.x;
    if (bid < ZPAD_BLKS) {
        const int buf = bid >> 5, rem = bid & 31;
        const int b = rem >> 1, row = (rem & 1) ? (LIN + 1) : 0;
        unsigned short* p = buf == 0 ? xb : (buf == 1 ? hbig : h2b);
        const int rl = buf == 1 ? DC : DM;
        unsigned short* base = p + ((size_t)b * (LIN + 2) + row) * rl;
        for (int c = tid; c < rl; c += 256) base[c] = 0;
        return;
    }
    if (bid < ZPAD_BLKS + CASTX_BLKS) {
        const int idx = (bid - ZPAD_BLKS) * 256 + tid;
        const float4 v = reinterpret_cast<const float4*>(x)[idx];
        const int e = idx * 4;
        const int b = e / (LIN * DM);
        const int rem = e - b * (LIN * DM);
        const int l = rem / DM;
        const int c = rem - l * DM;
        ushort4 o;
        o.x = f2bf(v.x); o.y = f2bf(v.y); o.z = f2bf(v.z); o.w = f2bf(v.w);
        *reinterpret_cast<ushort4*>(xb + ((size_t)b * (LIN + 2) + l + 1) * DM + c) = o;
        return;
    }
    if (bid < ZPAD_BLKS + CASTX_BLKS + 4 * WCAST_BLKS) {
        const int j = bid - ZPAD_BLKS - CASTX_BLKS;
        const int which = j / WCAST_BLKS;
        const int idx = (j - which * WCAST_BLKS) * 256 + tid;   // (co, ci-octet)
        const float* w = which == 0 ? w1 : which == 1 ? w2 : which == 2 ? w3 : w4;
        unsigned short* gg = which == 0 ? o1 : which == 1 ? o2 : which == 2 ? o3 : o4;
        const int CI = (which == 0 || which == 2) ? DM : DC;
        const int OCT = CI / 8;
        const int co = idx / OCT, ci0 = (idx - co * OCT) * 8;
        const float4* p4 = reinterpret_cast<const float4*>(w + (size_t)(co * CI + ci0) * 3);
        float v[24];
#pragma unroll
        for (int q = 0; q < 6; ++q) *reinterpret_cast<float4*>(&v[q * 4]) = p4[q];
        unsigned short tmp[3][8];
#pragma unroll
        for (int e = 0; e < 24; ++e) tmp[e % 3][e / 3] = f2bf(v[e]);
        unsigned short* ob = gg + (size_t)co * (3 * CI) + ci0;
#pragma unroll
        for (int t = 0; t < 3; ++t)
            *reinterpret_cast<uint4*>(ob + (size_t)t * CI) = *reinterpret_cast<const uint4*>(tmp[t]);
        return;
    }
    // ---- cumsum: one block per batch
    {
        const int b = bid - (ZPAD_BLKS + CASTX_BLKS + 4 * WCAST_BLKS);
        __shared__ int s[LIN];
        s[tid] = tgt[b * LIN + tid];
        s[tid + 256] = tgt[b * LIN + tid + 256];
        __syncthreads();
        for (int off = 1; off < LIN; off <<= 1) {
            int v0 = (tid >= off) ? s[tid - off] : 0;
            int v1 = (tid + 256 >= off) ? s[tid + 256 - off] : 0;
            __syncthreads();
            s[tid] += v0;
            s[tid + 256] += v1;
            __syncthreads();
        }
        cum[b * LIN + tid] = s[tid];
        cum[b * LIN + tid + 256] = s[tid + 256];
    }
}

// ---------------------------------------------------------------- conv1/3: 128M x 384N tile, 3-phase, 100% fill
// Grid 256 blocks (64 m-tiles x 4 n-tiles) = exactly 1/CU. 8 waves (2M x 4N);
// wave owns 64 M-rows x 96 N-cols, FRAG-INTERLEAVED over the 6 B-chunks:
// wave wcN's frag in chunk c = rows wcN*16+fr of chunk c (cols n0+c*64+wcN*16+fr).
// A (128x64, 16KB) read ONCE per K-tile into persistent aF[4][2]. B = 6 chunks
// of 64x64 (8KB, 1 gload_lds/thread each). LDS slot = A 16KB + B 48KB = 64KB,
// 2 slots = 128KB. 3 compute phases per K-tile (chunks {0,1},{2,3},{4,5}),
// 16 MFMA each. Stage ledger (8 loads/thread/tile): ph1 A(s1,k+1); ph2 B01(k+2);
// ph3 B23(k+2); tail B45(k+2); ONE vmcnt(6) per tile at tail (leaves B(k+2) in
// flight, drains A(k+1) + all older). Each stage target's last reader precedes
// it behind lgkm+barrier (chunk c read only at its phase; A(s1) read at prior
// tile's ph1). XOR swizzle both-sides (involution verified); 18-tile wrap keeps
// slot parity; final vmcnt(0) drains dead wrap-DMA.

__global__ __launch_bounds__(512, 2) void conv6_kernel(const unsigned short* __restrict__ in,
                                                       const unsigned short* __restrict__ wg,
                                                       const float* __restrict__ bias,
                                                       unsigned short* __restrict__ out) {
    constexpr int NKT = 18;                 // 1152 / 64
    __shared__ __align__(16) unsigned short smem[65536];   // 128 KB

    const int tid = threadIdx.x, lane = tid & 63, wv = tid >> 6;
    const int wrM = wv >> 2, wcN = wv & 3;  // 2M x 4N wave grid

    // bijective XCD swizzle over 256 blocks (= 8 * 32)
    const int orig = blockIdx.x;
    const int wgid = (orig & 7) * 32 + (orig >> 3);
    const int mg = wgid >> 2, ng = wgid & 3;   // n fastest
    const int b = mg >> 2, tm = mg & 3;        // 4 m-tiles (128) per batch
    const int n0 = ng * 384;

    const unsigned short* inb = in + ((size_t)b * (LIN + 2) + (size_t)tm * 128) * DM;

    const int fr = lane & 15, kg = lane >> 4;

    f32x4 acc[4][6];
#pragma unroll
    for (int i = 0; i < 4; ++i)
#pragma unroll
        for (int j = 0; j < 6; ++j) acc[i][j] = (f32x4){0.f, 0.f, 0.f, 0.f};

#define STG_A6(s, kt)                                                                     \
    do {                                                                                  \
        const int t_ = (kt) / 6, kc_ = (kt) - t_ * 6;                                     \
        _Pragma("unroll")                                                                 \
        for (int j = 0; j < 2; ++j) {                                                     \
            const int rr = (tid >> 3) + j * 64;                                           \
            const int e = ((tid & 7) * 8) ^ ((rr & 4) << 2);                              \
            GL2LDS(inb + (size_t)(t_ + rr) * DM + kc_ * 64 + e,                           \
                   smem + (s)*32768 + j * 4096 + tid * 8);                                \
        }                                                                                 \
    } while (0)

#define STG_B6(s, c, kt)                                                                  \
    do {                                                                                  \
        const int t_ = (kt) / 6, kc_ = (kt) - t_ * 6;                                     \
        const int rr = tid >> 3;                                                          \
        const int e = ((tid & 7) * 8) ^ ((rr & 4) << 2);                                  \
        GL2LDS(wg + (size_t)(n0 + (c)*64 + rr) * 1152 + t_ * 384 + kc_ * 64 + e,          \
               smem + (s)*32768 + 8192 + (c)*4096 + tid * 8);                             \
    } while (0)

#define LDA6(s)                                                                           \
    do {                                                                                  \
        _Pragma("unroll")                                                                 \
        for (int mf = 0; mf < 4; ++mf)                                                    \
            _Pragma("unroll")                                                             \
            for (int kh = 0; kh < 2; ++kh) {                                              \
                const int rr = wrM * 64 + mf * 16 + fr;                                   \
                const int ke = (kh * 32 + kg * 8) ^ ((rr & 4) << 2);                      \
                aF[mf][kh] = *reinterpret_cast<const bf16x8*>(                            \
                    smem + (s)*32768 + rr * 64 + ke);                                     \
            }                                                                             \
    } while (0)

#define LDB6(c, idx, s)                                                                   \
    do {                                                                                  \
        _Pragma("unroll")                                                                 \
        for (int kh = 0; kh < 2; ++kh) {                                                  \
            const int rr = wcN * 16 + fr;                                                 \
            const int ke = (kh * 32 + kg * 8) ^ ((rr & 4) << 2);                          \
            bF[idx][kh] = *reinterpret_cast<const bf16x8*>(                               \
                smem + (s)*32768 + 8192 + (c)*4096 + rr * 64 + ke);                       \
        }                                                                                 \
    } while (0)

#define MMA6(c, idx)                                                                      \
    do {                                                                                  \
        _Pragma("unroll")                                                                 \
        for (int mf = 0; mf < 4; ++mf)                                                    \
            _Pragma("unroll")                                                             \
            for (int kh = 0; kh < 2; ++kh)                                                \
                acc[mf][c] = __builtin_amdgcn_mfma_f32_16x16x32_bf16(                     \
                    aF[mf][kh], bF[idx][kh], acc[mf][c], 0, 0, 0);                        \
    } while (0)

    // ---- prologue: A(0) + B(0) all chunks + B(1) all chunks; drain to B(1) in flight
    STG_A6(0, 0);
#pragma unroll
    for (int c = 0; c < 6; ++c) STG_B6(0, c, 0);
#pragma unroll
    for (int c = 0; c < 6; ++c) STG_B6(1, c, 1);
    asm volatile("s_waitcnt vmcnt(6)" ::: "memory");
    asm volatile("s_barrier" ::: "memory");

#pragma unroll 1
    for (int m = 0; m < NKT; ++m) {
        const int s = m & 1, s1 = s ^ 1;
        int k1 = m + 1; if (k1 >= NKT) k1 -= NKT;
        int k2 = m + 2; if (k2 >= NKT) k2 -= NKT;
        bf16x8 aF[4][2], bF[2][2];
        // ph1: chunks 0,1 — full A read (persists), B frags c0,c1
        LDA6(s); LDB6(0, 0, s); LDB6(1, 1, s);
        STG_A6(s1, k1);                        // A(s1) last read: tile m-1 ph1 ✓
        asm volatile("s_barrier" ::: "memory");
        asm volatile("s_waitcnt lgkmcnt(0)" ::: "memory");
        __builtin_amdgcn_s_setprio(1); MMA6(0, 0); MMA6(1, 1); __builtin_amdgcn_s_setprio(0);
        asm volatile("s_barrier" ::: "memory");
        // ph2: chunks 2,3
        LDB6(2, 0, s); LDB6(3, 1, s);
        STG_B6(s, 0, k2); STG_B6(s, 1, k2);    // chunks 0,1 last read ph1 ✓
        asm volatile("s_barrier" ::: "memory");
        asm volatile("s_waitcnt lgkmcnt(0)" ::: "memory");
        __builtin_amdgcn_s_setprio(1); MMA6(2, 0); MMA6(3, 1); __builtin_amdgcn_s_setprio(0);
        asm volatile("s_barrier" ::: "memory");
        // ph3: chunks 4,5
        LDB6(4, 0, s); LDB6(5, 1, s);
        STG_B6(s, 2, k2); STG_B6(s, 3, k2);    // chunks 2,3 last read ph2 ✓
        asm volatile("s_barrier" ::: "memory");
        asm volatile("s_waitcnt lgkmcnt(0)" ::: "memory");
        __builtin_amdgcn_s_setprio(1); MMA6(4, 0); MMA6(5, 1); __builtin_amdgcn_s_setprio(0);
        asm volatile("s_barrier" ::: "memory");
        // tail: stage chunks 4,5 of k+2; the K-tile's single counted wait
        STG_B6(s, 4, k2); STG_B6(s, 5, k2);    // chunks 4,5 last read ph3 ✓
        asm volatile("s_waitcnt vmcnt(6)" ::: "memory");  // leaves B(k+2); drains A(k+1)+older
        asm volatile("s_barrier" ::: "memory");
    }
#undef STG_A6
#undef STG_B6
#undef LDA6
#undef LDB6
#undef MMA6
    asm volatile("s_waitcnt vmcnt(0)" ::: "memory");   // drain dead wrap-DMA

    // epilogue: bias + ReLU -> bf16; C/D layout col=lane&15, row=(lane>>4)*4+reg
    const int fq = lane >> 4;
    float bv[6];
#pragma unroll
    for (int c = 0; c < 6; ++c) bv[c] = bias[n0 + c * 64 + wcN * 16 + fr];
    unsigned short* outb = out + ((size_t)b * (LIN + 2) + (size_t)tm * 128 + 1) * DC;
#pragma unroll
    for (int mf = 0; mf < 4; ++mf)
#pragma unroll
        for (int qy = 0; qy < 4; ++qy) {
            const int r = wrM * 64 + mf * 16 + fq * 4 + qy;
            unsigned short* orow = outb + (size_t)r * DC + n0 + wcN * 16 + fr;
#pragma unroll
            for (int c = 0; c < 6; ++c) {
                const float v = fmaxf(acc[mf][c][qy] + bv[c], 0.f);
                orow[c * 64] = f2bf(v);
            }
        }
}

// ---------------------------------------------------------------- conv2/4: R7-exact counted-vmcnt kernel (BN=64)

template <int CI, int CO, int BN>
__global__ __launch_bounds__(256, 2) void conv_mfma_kernel(const unsigned short* __restrict__ in,
                                                           const unsigned short* __restrict__ wg,
                                                           const float* __restrict__ bias,
                                                           unsigned short* __restrict__ out) {
    constexpr int BM = 128, BK = 32;
    constexpr int KC = CI / BK;
    constexpr int AGRP = 12;
    constexpr int GPT = BN / 16;
    constexpr int BGRP = 3 * GPT;
    constexpr int NW_N = BN / 32;
    constexpr int NT = CO / BN;
    constexpr int NCONV = NB * (LIN / BM) * NT;

    __shared__ __align__(16) unsigned short As[2][AGRP * 512];
    __shared__ __align__(16) unsigned short Bs[2][BGRP * 512];

    const int tid = threadIdx.x;
    const int lane = tid & 63;
    const int wv = tid >> 6;

    const int orig = blockIdx.x;
    const int q = NCONV >> 3, xcd = orig & 7, o = orig >> 3;
    const int wgid = xcd * q + o;

    const int mg = wgid / NT;
    const int nt = wgid - mg * NT;
    const int b = mg >> 2;
    const int l0 = (mg & 3) * BM;
    const int n0 = nt * BN;

    const int wr = wv >> 1, wc = wv & 1;

    const unsigned short* inb = in + (size_t)b * (LIN + 2) * CI;

    f32x4 acc[4][NW_N];
#pragma unroll
    for (int m = 0; m < 4; ++m)
#pragma unroll
        for (int n = 0; n < NW_N; ++n) acc[m][n] = (f32x4){0.f, 0.f, 0.f, 0.f};

    const int lrow = lane >> 2;
    const int lch = lane & 3;
    const int fr = lane & 15, kg = lane >> 4;

    const unsigned short* aroot = inb + (size_t)l0 * CI + lch * 8;
    const unsigned short* broot = wg + (size_t)n0 * (3 * CI) + lch * 8;

#define STAGE(c, kb)                                                                      \
    do {                                                                                  \
        const unsigned short* abase = aroot + (kb) * BK;                                  \
        _Pragma("unroll")                                                                 \
        for (int g = wv; g < AGRP; g += 4) {                                              \
            const int sg = g < 9 ? g : 0;                                                 \
            GL2LDS(abase + (size_t)(sg * 16 + lrow) * CI, &As[c][g * 512]);               \
        }                                                                                 \
        const unsigned short* bbase = broot + (kb) * BK;                                  \
        _Pragma("unroll")                                                                 \
        for (int g2 = wv; g2 < BGRP; g2 += 4) {                                           \
            const int t = g2 / GPT, gr = g2 - t * GPT;                                    \
            GL2LDS(bbase + (size_t)(gr * 16 + lrow) * (3 * CI) + (size_t)t * CI,          \
                   &Bs[c][g2 * 512]);                                                     \
        }                                                                                 \
    } while (0)

#define COMPUTE(c)                                                                        \
    do {                                                                                  \
        _Pragma("unroll")                                                                 \
        for (int t = 0; t < 3; ++t) {                                                     \
            bf16x8 aF[4], bF[NW_N];                                                       \
            _Pragma("unroll")                                                             \
            for (int m = 0; m < 4; ++m)                                                   \
                aF[m] = *reinterpret_cast<const bf16x8*>(                                 \
                    &As[c][(t + wr * 64 + m * 16 + fr) * BK + kg * 8]);                   \
            _Pragma("unroll")                                                             \
            for (int n = 0; n < NW_N; ++n)                                                \
                bF[n] = *reinterpret_cast<const bf16x8*>(                                 \
                    &Bs[c][(t * BN + wc * (BN / 2) + n * 16 + fr) * BK + kg * 8]);        \
            _Pragma("unroll")                                                             \
            for (int m = 0; m < 4; ++m)                                                   \
                _Pragma("unroll")                                                         \
                for (int n = 0; n < NW_N; ++n)                                            \
                    acc[m][n] =                                                           \
                        __builtin_amdgcn_mfma_f32_16x16x32_bf16(aF[m], bF[n], acc[m][n],  \
                                                                0, 0, 0);                 \
        }                                                                                 \
    } while (0)

    STAGE(0, 0);
    STAGE(1, 1);
#pragma unroll 1
    for (int kb = 0; kb < KC; ++kb) {
        const int cur = kb & 1;
        if constexpr (BN == 128)
            asm volatile("s_waitcnt vmcnt(9)" ::: "memory");
        else
            asm volatile("s_waitcnt vmcnt(6)" ::: "memory");
        __builtin_amdgcn_sched_barrier(0);
        __builtin_amdgcn_s_barrier();
        __builtin_amdgcn_sched_barrier(0);
        COMPUTE(cur);
        asm volatile("s_waitcnt lgkmcnt(0)" ::: "memory");
        __builtin_amdgcn_sched_barrier(0);
        __builtin_amdgcn_s_barrier();
        __builtin_amdgcn_sched_barrier(0);
        int nk = kb + 2;
        if (nk >= KC) nk -= KC;
        STAGE(cur, nk);
    }
#undef STAGE
#undef COMPUTE
    asm volatile("s_waitcnt vmcnt(0)" ::: "memory");

    const int fq = lane >> 4;
    float bv[NW_N];
#pragma unroll
    for (int n = 0; n < NW_N; ++n) bv[n] = bias[n0 + wc * (BN / 2) + n * 16 + fr];
    unsigned short* outb = out + (size_t)b * (LIN + 2) * CO;
#pragma unroll
    for (int m = 0; m < 4; ++m)
#pragma unroll
        for (int qy = 0; qy < 4; ++qy) {
            const int grow = l0 + wr * 64 + m * 16 + fq * 4 + qy + 1;
            unsigned short* orow = outb + (size_t)grow * CO + n0 + wc * (BN / 2) + fr;
#pragma unroll
            for (int n = 0; n < NW_N; ++n) {
                const float v = fmaxf(acc[m][n][qy] + bv[n], 0.f);
                orow[n * 16] = f2bf(v);
            }
        }
}

// ---------------------------------------------------------------- LayerNorm (4 rows per block, in place)

__global__ __launch_bounds__(256) void ln_kernel(unsigned short* __restrict__ h,
                                                 const float* __restrict__ g,
                                                 const float* __restrict__ be) {
    const int row = blockIdx.x * 4 + (threadIdx.x >> 6);
    const int lane = threadIdx.x & 63;
    const int b = row >> 9, l = row & (LIN - 1);
    unsigned short* hr = h + ((size_t)b * (LIN + 2) + l + 1) * DM;
    float v[6];
    float s = 0.f;
#pragma unroll
    for (int j = 0; j < 6; ++j) { v[j] = bf2f(hr[lane + 64 * j]); s += v[j]; }
    s = wred(s);
    const float mean = s * (1.f / DM);
    float vs = 0.f;
#pragma unroll
    for (int j = 0; j < 6; ++j) { const float d = v[j] - mean; vs += d * d; }
    vs = wred(vs);
    const float rstd = rsqrtf(vs * (1.f / DM) + LN_EPS);
#pragma unroll
    for (int j = 0; j < 6; ++j) {
        const int c = lane + 64 * j;
        hr[c] = f2bf((v[j] - mean) * rstd * g[c] + be[c]);
    }
}

// ---------------------------------------------------------------- LayerNorm + linear(384->1), 4 rows/block

__global__ __launch_bounds__(256) void ln_linear_kernel(const unsigned short* __restrict__ h,
                                                        const float* __restrict__ g,
                                                        const float* __restrict__ be,
                                                        const float* __restrict__ wl,
                                                        const float* __restrict__ bl,
                                                        float* __restrict__ dur) {
    const int row = blockIdx.x * 4 + (threadIdx.x >> 6);
    const int lane = threadIdx.x & 63;
    const int b = row >> 9, l = row & (LIN - 1);
    const unsigned short* hr = h + ((size_t)b * (LIN + 2) + l + 1) * DM;
    float v[6];
    float s = 0.f;
#pragma unroll
    for (int j = 0; j < 6; ++j) { v[j] = bf2f(hr[lane + 64 * j]); s += v[j]; }
    s = wred(s);
    const float mean = s * (1.f / DM);
    float vs = 0.f;
#pragma unroll
    for (int j = 0; j < 6; ++j) { const float d = v[j] - mean; vs += d * d; }
    vs = wred(vs);
    const float rstd = rsqrtf(vs * (1.f / DM) + LN_EPS);
    float dot = 0.f;
#pragma unroll
    for (int j = 0; j < 6; ++j) {
        const int c = lane + 64 * j;
        dot += ((v[j] - mean) * rstd * g[c] + be[c]) * wl[c];
    }
    dot = wred(dot);
    if (lane == 0) dur[row] = dot + bl[0];
}

// ---------------------------------------------------------------- launch

extern "C" void kernel_launch(void* const* d_in, const int* in_sizes, int n_in,
                              void* d_out, int out_size, void* d_ws, size_t ws_size,
                              hipStream_t stream) {
    const float* x   = (const float*)d_in[0];
    const int*   tgt = (const int*)d_in[1];
    const float* w1  = (const float*)d_in[3];
    const float* b1  = (const float*)d_in[4];
    const float* w2  = (const float*)d_in[5];
    const float* b2  = (const float*)d_in[6];
    const float* g1  = (const float*)d_in[7];
    const float* be1 = (const float*)d_in[8];
    const float* w3  = (const float*)d_in[9];
    const float* b3  = (const float*)d_in[10];
    const float* w4  = (const float*)d_in[11];
    const float* b4  = (const float*)d_in[12];
    const float* g2  = (const float*)d_in[13];
    const float* be2 = (const float*)d_in[14];
    const float* wl  = (const float*)d_in[15];
    const float* bl  = (const float*)d_in[16];

    float* out = (float*)d_out;                         // (16, 4096, 384) f32
    float* dur = out + (size_t)NB * MELMAX * DM;        // (16, 512) f32

    unsigned short* ws = (unsigned short*)d_ws;
    unsigned short* xb   = ws;                                 // (16, 514, 384)  also conv4 out
    unsigned short* hbig = xb + (size_t)NB * (LIN + 2) * DM;   // (16, 514, 1536) conv1/conv3 out
    unsigned short* h2b  = hbig + (size_t)NB * (LIN + 2) * DC; // (16, 514, 384)  conv2 out
    unsigned short* wg1  = h2b + (size_t)NB * (LIN + 2) * DM;  // (1536, 1152)
    unsigned short* wg2  = wg1 + (size_t)DC * 3 * DM;          // (384, 4608)
    unsigned short* wg3  = wg2 + (size_t)DM * 3 * DC;          // (1536, 1152)
    unsigned short* wg4  = wg3 + (size_t)DC * 3 * DM;          // (384, 4608)
    int* cum = (int*)(wg4 + (size_t)DM * 3 * DC);              // (16, 512)

    // ---- prep (zpad + cast_x + wcast + cumsum, one launch)
    prep_kernel<<<PREP_TOTAL, 256, 0, stream>>>(x, xb, hbig, h2b, w1, w2, w3, w4,
                                                wg1, wg2, wg3, wg4, tgt, cum);

    // ---- output 0: length regulate
    gather_kernel<<<(NB * MELMAX) / 4, 256, 0, stream>>>(x, cum, out);

    // ---- output 1: duration predictor
    // conv1/3: 128x384 3-phase kernel, grid 256 = 100% fill; conv2/4: R7 counted-vmcnt
    conv6_kernel<<<256, 512, 0, stream>>>(xb, wg1, b1, hbig);
    conv_mfma_kernel<DC, DM, 64><<<NB * (LIN / 128) * (DM / 64), 256, 0, stream>>>(hbig, wg2, b2, h2b);
    ln_kernel<<<NB * LIN / 4, 256, 0, stream>>>(h2b, g1, be1);
    conv6_kernel<<<256, 512, 0, stream>>>(h2b, wg3, b3, hbig);
    conv_mfma_kernel<DC, DM, 64><<<NB * (LIN / 128) * (DM / 64), 256, 0, stream>>>(hbig, wg4, b4, xb);
    ln_linear_kernel<<<NB * LIN / 4, 256, 0, stream>>>(xb, g2, be2, wl, bl, dur);
}